// Round 3
// baseline (29.999 us; speedup 1.0000x reference)
//
#include <hip/hip_runtime.h>
#include <hip/hip_bf16.h>

// B=64, S=512, N=32768, D=256, H=4, HD=64, T=24, scale=1/8.
//
// Workspace layout (float offsets):
//   qu  [64][256]        @ 0       (16384)  Wq(:, :256) @ user_pref[user[b]]
//   qt  [24][256]        @ 16384   (6144)   Wq(:, 256:) @ ts[t] + bq
//   kk  [96][64]         @ 22528   (6144)   (h*24+t major) Wk @ ts + bk
//   vv  [96][64]         @ 28672   (6144)   Wv @ ts + bv
//   EU  [64][4][24]      @ 34816   (6144)   exp(scale * qu.k)
//   ET  [24][4][24]      @ 40960   (2304)   exp(scale * qt.k)
//   vWB [96x256 bf16]    @ 43264   (12288 floats) folded V*Wu in MFMA-B fragment layout
#define QU_OFF   0
#define QT_OFF   16384
#define KK_OFF   22528
#define VV_OFF   28672
#define EU_OFF   34816
#define ET_OFF   40960
#define VWB_OFF  43264

typedef __attribute__((ext_vector_type(8))) short bf16x8;
typedef __attribute__((ext_vector_type(4))) float f32x4;

__device__ __forceinline__ unsigned short f2bf(float f) {
    unsigned u = __builtin_bit_cast(unsigned, f);
    return (unsigned short)((u + 0x7FFFu + ((u >> 16) & 1u)) >> 16);
}

// ---------- Kernel P1: qu/qt/kk/vv projections, GEMV-style ----------
// 136 blocks x 256 thr. Block stages shared x (256 f) in LDS; thread owns
// one output row j, streams W[j] as float4 (L1-line reuse), x via LDS bcast.
__global__ __launch_bounds__(256) void precomp1(
    const float* __restrict__ ts, const int* __restrict__ user,
    const float* __restrict__ user_pref,
    const float* __restrict__ Wq, const float* __restrict__ bq,
    const float* __restrict__ Wk, const float* __restrict__ bk,
    const float* __restrict__ Wv, const float* __restrict__ bv,
    float* __restrict__ ws)
{
    __shared__ float xs[256];
    int tid = threadIdx.x, blk = blockIdx.x;
    int lane = tid & 63, jb = tid >> 6;
    int j = tid;                               // output row 0..255
    const float* W; const float* xsrc;
    int ldw, coff; float bval; float* outp;
    if (blk < 64) {                            // qu[b]
        xsrc = user_pref + (size_t)user[blk] * 256;
        W = Wq; ldw = 512; coff = 0; bval = 0.f;
        outp = ws + QU_OFF + blk * 256 + j;
    } else if (blk < 88) {                     // qt[t]
        int t = blk - 64;
        xsrc = ts + t * 256; W = Wq; ldw = 512; coff = 256; bval = bq[j];
        outp = ws + QT_OFF + t * 256 + j;
    } else if (blk < 112) {                    // kk[t] -> [h*24+t][hd]
        int t = blk - 88;
        xsrc = ts + t * 256; W = Wk; ldw = 256; coff = 0; bval = bk[j];
        outp = ws + KK_OFF + (jb * 24 + t) * 64 + lane;
    } else {                                   // vv[t]
        int t = blk - 112;
        xsrc = ts + t * 256; W = Wv; ldw = 256; coff = 0; bval = bv[j];
        outp = ws + VV_OFF + (jb * 24 + t) * 64 + lane;
    }
    xs[tid] = xsrc[tid];
    __syncthreads();
    const float4* wr  = (const float4*)(W + (size_t)j * ldw + coff);
    const float4* xv4 = (const float4*)xs;
    float s = 0.f;
    #pragma unroll 16
    for (int k = 0; k < 64; ++k) {
        float4 w4 = wr[k]; float4 x4 = xv4[k];
        s = fmaf(w4.x, x4.x, fmaf(w4.y, x4.y, fmaf(w4.z, x4.z, fmaf(w4.w, x4.w, s))));
    }
    *outp = s + bval;
}

// ---------- Kernel P2: folded tables (vWB bf16 B-frag layout, EU, ET) ----------
__global__ __launch_bounds__(256) void precomp2(float* __restrict__ ws,
                                                const float* __restrict__ Wu)
{
    const float* qu = ws + QU_OFF;
    const float* qt = ws + QT_OFF;
    const float* kk = ws + KK_OFF;
    const float* vv = ws + VV_OFF;
    int o = blockIdx.x * 256 + threadIdx.x;
    if (o < 12288) {                          // vWB: thread = (ht-pair, d)
        int htp = o >> 8, d = o & 255;
        int ht = htp * 2;
        int h = ht / 24;                      // pair never crosses h (24 even)
        const float4* v0 = (const float4*)(vv + ht * 64);
        const float4* v1 = (const float4*)(vv + ht * 64 + 64);
        const float4* wp = (const float4*)(Wu + d * 256 + h * 64);
        float s0 = 0.f, s1 = 0.f;
        #pragma unroll
        for (int i = 0; i < 16; ++i) {
            float4 wv = wp[i], a = v0[i], c = v1[i];
            s0 = fmaf(a.x, wv.x, fmaf(a.y, wv.y, fmaf(a.z, wv.z, fmaf(a.w, wv.w, s0))));
            s1 = fmaf(c.x, wv.x, fmaf(c.y, wv.y, fmaf(c.z, wv.z, fmaf(c.w, wv.w, s1))));
        }
        // B-frag: (k=ht, col=d) -> lane=(d&15)+16*((ht>>3)&3), word j=(ht&7)>>1
        int kt = ht >> 5, nt = d >> 4, lg = (ht >> 3) & 3, jh = (ht & 7) >> 1;
        unsigned pack = (unsigned)f2bf(s0) | ((unsigned)f2bf(s1) << 16);
        ((unsigned*)(ws + VWB_OFF))[(kt * 16 + nt) * 256 + ((d & 15) + 16 * lg) * 4 + jh] = pack;
    } else if (o < 18432) {                   // EU[b][h*24+t]
        int o2 = o - 12288;
        int b = o2 / 96, rem = o2 - b * 96;
        const float4* qp = (const float4*)(qu + b * 256 + (rem / 24) * 64);
        const float4* kp = (const float4*)(kk + rem * 64);
        float s = 0.f;
        #pragma unroll
        for (int i = 0; i < 16; ++i) {
            float4 a = qp[i], c = kp[i];
            s = fmaf(a.x, c.x, fmaf(a.y, c.y, fmaf(a.z, c.z, fmaf(a.w, c.w, s))));
        }
        ws[EU_OFF + o2] = expf(s * 0.125f);
    } else if (o < 20736) {                   // ET[t'][h*24+t]
        int o3 = o - 18432;
        int tp = o3 / 96, rem = o3 - tp * 96;
        const float4* qp = (const float4*)(qt + tp * 256 + (rem / 24) * 64);
        const float4* kp = (const float4*)(kk + rem * 64);
        float s = 0.f;
        #pragma unroll
        for (int i = 0; i < 16; ++i) {
            float4 a = qp[i], c = kp[i];
            s = fmaf(a.x, c.x, fmaf(a.y, c.y, fmaf(a.z, c.z, fmaf(a.w, c.w, s))));
        }
        ws[ET_OFF + o3] = expf(s * 0.125f);
    }
}

// ---------- Kernel C: 128 tok/block; B staged via regs->LDS; MFMA GEMM ----------
__global__ __launch_bounds__(512) void attn_mfma(
    const int* __restrict__ hour, const int* __restrict__ hour_mask,
    const float* __restrict__ ws, const float* __restrict__ bu,
    float* __restrict__ out)
{
    const float* EU = ws + EU_OFF;
    const float* ET = ws + ET_OFF;
    __shared__ int4 B_lds[48 * 64];           // 48 KB: [frag][lane]
    __shared__ int4 A_lds[24 * 64];           // 24 KB: [(kt*8+mt8)][lane]
    int tid = threadIdx.x, w = tid >> 6, l = tid & 63;
    int nb = blockIdx.x * 128;                // 128 tokens/block, all same b
    int b = nb >> 9;
    // ---- issue B-fragment loads early (T14); latency hides under phase 1 ----
    const int4* Bg = (const int4*)(ws + VWB_OFF);
    int4 breg[6];
    #pragma unroll
    for (int i = 0; i < 6; ++i) breg[i] = Bg[(w * 6 + i) * 64 + l];
    // ---- phase 1: attention probs, thread = (tok, h); write bf16 A-fragments ----
    {
        int tok = tid >> 2, h = tid & 3;
        int n = nb + tok;
        int th = hour[n];
        const float4* EUp = (const float4*)(EU + b * 96 + h * 24);
        const float4* ETp = (const float4*)(ET + th * 96 + h * 24);
        const int4*   mp  = (const int4*)(hour_mask + (long long)n * 24);
        float p[24]; float ssum = 0.f;
        #pragma unroll
        for (int q = 0; q < 6; ++q) {
            float4 e = EUp[q]; float4 f = ETp[q]; int4 m = mp[q];
            float v0 = (m.x != 0) ? 0.f : e.x * f.x;
            float v1 = (m.y != 0) ? 0.f : e.y * f.y;
            float v2 = (m.z != 0) ? 0.f : e.z * f.z;
            float v3 = (m.w != 0) ? 0.f : e.w * f.w;
            p[q*4+0] = v0; p[q*4+1] = v1; p[q*4+2] = v2; p[q*4+3] = v3;
            ssum += (v0 + v1) + (v2 + v3);
        }
        float r = 1.0f / ssum;
        int mt8 = tok >> 4, tl = tok & 15;
        #pragma unroll
        for (int tp = 0; tp < 12; ++tp) {
            int ht = h * 24 + tp * 2;         // even; pair (ht, ht+1)
            unsigned pack = (unsigned)f2bf(p[tp*2] * r)
                          | ((unsigned)f2bf(p[tp*2+1] * r) << 16);
            int kt = ht >> 5, lg = (ht >> 3) & 3, jh = (ht & 7) >> 1;
            ((unsigned*)A_lds)[((kt * 8 + mt8) * 64 + tl + 16 * lg) * 4 + jh] = pack;
        }
    }
    // ---- park B fragments in LDS ----
    #pragma unroll
    for (int i = 0; i < 6; ++i) B_lds[(w * 6 + i) * 64 + l] = breg[i];
    __syncthreads();
    // ---- phase 2: wave (mh, ns): 4 M-tiles x 4 N-tiles x 3 K-chunks MFMA ----
    int mh = w >> 2, ns = w & 3;
    bf16x8 afr[3][4], bfr[3][4];
    #pragma unroll
    for (int kt = 0; kt < 3; ++kt)
        #pragma unroll
        for (int q = 0; q < 4; ++q) {
            afr[kt][q] = __builtin_bit_cast(bf16x8, A_lds[(kt * 8 + mh * 4 + q) * 64 + l]);
            bfr[kt][q] = __builtin_bit_cast(bf16x8, B_lds[(kt * 16 + ns * 4 + q) * 64 + l]);
        }
    f32x4 acc[4][4];
    #pragma unroll
    for (int mt = 0; mt < 4; ++mt)
        #pragma unroll
        for (int q = 0; q < 4; ++q) acc[mt][q] = (f32x4)0.f;
    #pragma unroll
    for (int kt = 0; kt < 3; ++kt)
        #pragma unroll
        for (int mt = 0; mt < 4; ++mt)
            #pragma unroll
            for (int q = 0; q < 4; ++q)
                acc[mt][q] = __builtin_amdgcn_mfma_f32_16x16x32_bf16(
                    afr[kt][mt], bfr[kt][q], acc[mt][q], 0, 0, 0);
    // ---- epilogue: + bu, store (D: col=l&15, row=(l>>4)*4+reg) ----
    int colb = ns * 64 + (l & 15);
    float buv[4];
    #pragma unroll
    for (int q = 0; q < 4; ++q) buv[q] = bu[colb + q * 16];
    int row0 = nb + mh * 64 + (l >> 4) * 4;
    #pragma unroll
    for (int mt = 0; mt < 4; ++mt)
        #pragma unroll
        for (int q = 0; q < 4; ++q) {
            float* op = out + (size_t)(row0 + mt * 16) * 256 + colb + q * 16;
            #pragma unroll
            for (int r = 0; r < 4; ++r)
                op[(size_t)r * 256] = acc[mt][q][r] + buv[q];
        }
}

extern "C" void kernel_launch(void* const* d_in, const int* in_sizes, int n_in,
                              void* d_out, int out_size, void* d_ws, size_t ws_size,
                              hipStream_t stream)
{
    const float* ts        = (const float*)d_in[0];
    const int*   user      = (const int*)  d_in[1];
    const int*   hour      = (const int*)  d_in[2];
    const int*   hour_mask = (const int*)  d_in[3];
    const float* user_pref = (const float*)d_in[4];
    const float* Wq        = (const float*)d_in[5];
    const float* bq        = (const float*)d_in[6];
    const float* Wk        = (const float*)d_in[7];
    const float* bk        = (const float*)d_in[8];
    const float* Wv        = (const float*)d_in[9];
    const float* bv        = (const float*)d_in[10];
    const float* Wu        = (const float*)d_in[11];
    const float* bu        = (const float*)d_in[12];
    float* ws  = (float*)d_ws;
    float* out = (float*)d_out;

    hipLaunchKernelGGL(precomp1, dim3(136), dim3(256), 0, stream,
                       ts, user, user_pref, Wq, bq, Wk, bk, Wv, bv, ws);
    hipLaunchKernelGGL(precomp2, dim3(81), dim3(256), 0, stream, ws, Wu);
    hipLaunchKernelGGL(attn_mfma, dim3(256), dim3(512), 0, stream,
                       hour, hour_mask, ws, bu, out);
}